// Round 1
// 1142.001 us; speedup vs baseline: 1.0171x; 1.0171x over previous
//
#include <hip/hip_runtime.h>
#include <hip/hip_bf16.h>
#include <stdint.h>

// ---------------------------------------------------------------------------
// SparseQuantLinear: out[m,o] = sum_i x[m,i] * W[o,i] + bias[o]
//   W[o,i] = mask[o,i] ? (W_q[o,i] - zeros[o,i/G]) * scales[o,i/G] * scale2[i] : 0
//
// R2 plan (this round):
//   1. dequant W -> bf16 Wb in ws (32 MB)                    [unchanged math]
//   2. convert X fp32 -> bf16 Xb in ws (+128 MB)             [new, one pass]
//   3. m97-structure GEMM: BOTH operands staged into LINEAR LDS via
//      __builtin_amdgcn_global_load_lds width=16 (the measured +69% lever),
//      2-barrier K-loop, 128x128 tile, 4 waves, 16x16x32 bf16 MFMA.
//   Fallback: if ws_size < 160 MB, use the previous (verified) fp32-A gemm.
// ---------------------------------------------------------------------------

typedef short s16x8 __attribute__((ext_vector_type(8)));   // 8 bf16 bit-patterns
typedef short s16x4 __attribute__((ext_vector_type(4)));
typedef float f32x4 __attribute__((ext_vector_type(4)));

#define BM 128
#define BN 128
#define BK 64
#define LDSS 72   // padded stride for the fallback kernel only

static __device__ __forceinline__ short f2bf(float f) {
    __hip_bfloat16 h = __float2bfloat16(f);   // round-to-nearest-even
    return *reinterpret_cast<short*>(&h);
}

// ---------------- dequant: W_q(int32) -> W bf16 bits (short) ----------------
__global__ __launch_bounds__(256)
void dequant_kernel(const int* __restrict__ Wq,
                    const float* __restrict__ scales,
                    const float* __restrict__ zeros,
                    const void* __restrict__ mask_raw,
                    const float* __restrict__ scale2,
                    short* __restrict__ Wb,
                    int O, int I, int G) {
    // --- mask dtype probe (uniform across grid; ~1KB, L2-resident) ---
    __shared__ int lds_flag;
    if (threadIdx.x == 0) lds_flag = 0;
    __syncthreads();
    {
        unsigned v = ((const unsigned*)mask_raw)[threadIdx.x & 255];
        if (v > 1u) lds_flag = 1;          // benign same-value race
    }
    __syncthreads();
    const bool mask_is_byte = (lds_flag != 0);

    int idx = (blockIdx.x * 256 + threadIdx.x) * 8;   // O*I = 16.7M fits int
    if (idx >= O * I) return;
    int o = idx / I;
    int i = idx - o * I;              // multiple of 8; G=128 -> one group per 8
    int gi = o * (I / G) + i / G;
    float s = scales[gi];
    float z = zeros[gi];

    int4 w0 = *(const int4*)(Wq + idx);
    int4 w1 = *(const int4*)(Wq + idx + 4);
    float4 s2a = *(const float4*)(scale2 + i);
    float4 s2b = *(const float4*)(scale2 + i + 4);

    unsigned m[8];
    if (mask_is_byte) {
        unsigned long long mb = *(const unsigned long long*)((const unsigned char*)mask_raw + idx);
        #pragma unroll
        for (int j = 0; j < 8; ++j) m[j] = (unsigned)((mb >> (8 * j)) & 0xffULL);
    } else {
        int4 ma = *(const int4*)((const int*)mask_raw + idx);
        int4 mbv = *(const int4*)((const int*)mask_raw + idx + 4);
        m[0] = ma.x;  m[1] = ma.y;  m[2] = ma.z;  m[3] = ma.w;
        m[4] = mbv.x; m[5] = mbv.y; m[6] = mbv.z; m[7] = mbv.w;
    }

    float v[8];
    v[0] = ((float)w0.x - z) * s * s2a.x;
    v[1] = ((float)w0.y - z) * s * s2a.y;
    v[2] = ((float)w0.z - z) * s * s2a.z;
    v[3] = ((float)w0.w - z) * s * s2a.w;
    v[4] = ((float)w1.x - z) * s * s2b.x;
    v[5] = ((float)w1.y - z) * s * s2b.y;
    v[6] = ((float)w1.z - z) * s * s2b.z;
    v[7] = ((float)w1.w - z) * s * s2b.w;

    union { s16x8 v; int4 q; } out;
    #pragma unroll
    for (int j = 0; j < 8; ++j) {
        float masked = m[j] ? v[j] : 0.0f;
        out.v[j] = f2bf(masked);
    }
    *(int4*)(Wb + idx) = out.q;
}

// ---------------- convert: X fp32 -> bf16 (one pass) ------------------------
__global__ __launch_bounds__(256)
void convert_x_kernel(const float* __restrict__ X, short* __restrict__ Xb, int n8) {
    int c = blockIdx.x * 256 + threadIdx.x;
    if (c >= n8) return;
    size_t idx = (size_t)c * 8;
    float4 a = *(const float4*)(X + idx);
    float4 b = *(const float4*)(X + idx + 4);
    union { s16x8 v; int4 q; } o;
    o.v[0] = f2bf(a.x); o.v[1] = f2bf(a.y); o.v[2] = f2bf(a.z); o.v[3] = f2bf(a.w);
    o.v[4] = f2bf(b.x); o.v[5] = f2bf(b.y); o.v[6] = f2bf(b.z); o.v[7] = f2bf(b.w);
    *(int4*)(Xb + idx) = o.q;
}

// ---------------- bf16 MFMA GEMM (m97 structure): Out = Xb * Wb^T + bias ----
// Linear LDS (no pad) + global_load_lds width=16 for both operands.
// LDS dest is wave-uniform base + lane*16 (HW rule), so chunks are laid out
// lane-consecutive: chunk c = tid + t*256 covers bytes [c*16, c*16+16) of the
// linearized [128][64]-bf16 tile (row = c>>3, col = (c&7)*8).
__global__ __launch_bounds__(256, 2)
void gemm_bb_kernel(const short* __restrict__ Xb,
                    const short* __restrict__ Wb,
                    const float* __restrict__ bias,
                    float* __restrict__ Out,
                    int M, int N, int K) {
    __shared__ short As[BM * BK];   // 16 KiB, linear
    __shared__ short Bs[BN * BK];   // 16 KiB, linear

    const int tid  = threadIdx.x;
    const int m0   = blockIdx.y * BM;
    const int n0   = blockIdx.x * BN;
    const int wave = tid >> 6;
    const int lane = tid & 63;
    const int wm   = (wave >> 1) * 64;   // wave row offset in tile
    const int wn   = (wave & 1) * 64;    // wave col offset in tile
    const int lr   = lane & 15;          // row (A) / col (B) within 16
    const int lq   = lane >> 4;          // quad -> k offset lq*8, C rows lq*4

    f32x4 acc[4][4] = {};

    // per-thread global staging coords (constant across K loop):
    // chunk c = tid + t*256 -> row = (tid>>3) + t*32, col = (tid&7)*8
    const short* gA = Xb + (size_t)(m0 + (tid >> 3)) * K + (tid & 7) * 8;
    const short* gB = Wb + (size_t)(n0 + (tid >> 3)) * K + (tid & 7) * 8;
    // wave-uniform LDS bases (lane*16B added by hardware)
    short* lA = &As[wave * 512];
    short* lB = &Bs[wave * 512];

    for (int k0 = 0; k0 < K; k0 += BK) {
        #pragma unroll
        for (int t = 0; t < 4; ++t) {
            __builtin_amdgcn_global_load_lds(
                (const __attribute__((address_space(1))) void*)(gA + (size_t)t * 32 * K + k0),
                (__attribute__((address_space(3))) void*)(lA + t * 2048), 16, 0, 0);
            __builtin_amdgcn_global_load_lds(
                (const __attribute__((address_space(1))) void*)(gB + (size_t)t * 32 * K + k0),
                (__attribute__((address_space(3))) void*)(lB + t * 2048), 16, 0, 0);
        }
        __syncthreads();   // compiler emits vmcnt(0) drain before s_barrier

        #pragma unroll
        for (int kk = 0; kk < BK; kk += 32) {
            s16x8 af[4], bfv[4];
            #pragma unroll
            for (int mi = 0; mi < 4; ++mi)
                af[mi] = *(const s16x8*)&As[(wm + mi * 16 + lr) * BK + kk + lq * 8];
            #pragma unroll
            for (int ni = 0; ni < 4; ++ni)
                bfv[ni] = *(const s16x8*)&Bs[(wn + ni * 16 + lr) * BK + kk + lq * 8];
            #pragma unroll
            for (int mi = 0; mi < 4; ++mi)
                #pragma unroll
                for (int ni = 0; ni < 4; ++ni)
                    acc[mi][ni] = __builtin_amdgcn_mfma_f32_16x16x32_bf16(
                        af[mi], bfv[ni], acc[mi][ni], 0, 0, 0);
        }
        __syncthreads();
    }

    // epilogue: C/D layout col = lane&15, row = lq*4 + r   (m89/m91 verified)
    #pragma unroll
    for (int ni = 0; ni < 4; ++ni) {
        int nc = n0 + wn + ni * 16 + lr;
        float bv = bias[nc];
        #pragma unroll
        for (int mi = 0; mi < 4; ++mi) {
            int mr = m0 + wm + mi * 16 + lq * 4;
            #pragma unroll
            for (int r = 0; r < 4; ++r)
                Out[(size_t)(mr + r) * N + nc] = acc[mi][ni][r] + bv;
        }
    }
}

// ---------------- fallback GEMM (previous verified kernel, fp32 A) ----------
__global__ __launch_bounds__(256, 2)
void gemm_kernel(const float* __restrict__ X,
                 const short* __restrict__ Wb,
                 const float* __restrict__ bias,
                 float* __restrict__ Out,
                 int M, int N, int K) {
    __shared__ short As[BM * LDSS];
    __shared__ short Bs[BN * LDSS];

    const int tid  = threadIdx.x;
    const int m0   = blockIdx.y * BM;
    const int n0   = blockIdx.x * BN;
    const int wave = tid >> 6;
    const int lane = tid & 63;
    const int wm   = (wave >> 1) * 64;
    const int wn   = (wave & 1) * 64;
    const int lr   = lane & 15;
    const int lq   = lane >> 4;

    f32x4 acc[4][4] = {};

    for (int k0 = 0; k0 < K; k0 += BK) {
        #pragma unroll
        for (int t = 0; t < 8; ++t) {
            int c   = tid + t * 256;
            int row = c >> 4;
            int col = (c & 15) * 4;
            float4 xv = *(const float4*)(X + (size_t)(m0 + row) * K + k0 + col);
            s16x4 bv;
            bv[0] = f2bf(xv.x); bv[1] = f2bf(xv.y);
            bv[2] = f2bf(xv.z); bv[3] = f2bf(xv.w);
            *(s16x4*)&As[row * LDSS + col] = bv;
        }
        #pragma unroll
        for (int t = 0; t < 4; ++t) {
            int c   = tid + t * 256;
            int row = c >> 3;
            int col = (c & 7) * 8;
            s16x8 wv = *(const s16x8*)(Wb + (size_t)(n0 + row) * K + k0 + col);
            *(s16x8*)&Bs[row * LDSS + col] = wv;
        }
        __syncthreads();

        #pragma unroll
        for (int kk = 0; kk < BK; kk += 32) {
            s16x8 af[4], bf[4];
            #pragma unroll
            for (int mi = 0; mi < 4; ++mi)
                af[mi] = *(const s16x8*)&As[(wm + mi * 16 + lr) * LDSS + kk + lq * 8];
            #pragma unroll
            for (int ni = 0; ni < 4; ++ni)
                bf[ni] = *(const s16x8*)&Bs[(wn + ni * 16 + lr) * LDSS + kk + lq * 8];
            #pragma unroll
            for (int mi = 0; mi < 4; ++mi)
                #pragma unroll
                for (int ni = 0; ni < 4; ++ni)
                    acc[mi][ni] = __builtin_amdgcn_mfma_f32_16x16x32_bf16(
                        af[mi], bf[ni], acc[mi][ni], 0, 0, 0);
        }
        __syncthreads();
    }

    #pragma unroll
    for (int ni = 0; ni < 4; ++ni) {
        int nc = n0 + wn + ni * 16 + lr;
        float bv = bias[nc];
        #pragma unroll
        for (int mi = 0; mi < 4; ++mi) {
            int mr = m0 + wm + mi * 16 + lq * 4;
            #pragma unroll
            for (int r = 0; r < 4; ++r)
                Out[(size_t)(mr + r) * N + nc] = acc[mi][ni][r] + bv;
        }
    }
}

// ---------------------------------------------------------------------------
extern "C" void kernel_launch(void* const* d_in, const int* in_sizes, int n_in,
                              void* d_out, int out_size, void* d_ws, size_t ws_size,
                              hipStream_t stream) {
    const float* x      = (const float*)d_in[0];
    const int*   Wq     = (const int*)d_in[1];
    const float* scales = (const float*)d_in[2];
    const float* zeros  = (const float*)d_in[3];
    const void*  mask   = (const void*)d_in[4];   // bool: byte OR int32 (auto-detect)
    const float* scale2 = (const float*)d_in[5];
    const float* bias   = (const float*)d_in[6];
    float*       out    = (float*)d_out;

    const int I = in_sizes[5];                       // 4096
    const int O = in_sizes[6];                       // 4096
    const int M = (int)(in_sizes[0] / I);            // 16384
    const int G = (int)(((long long)O * I) / in_sizes[2]);  // 128

    short* Wb = (short*)d_ws;                        // O*I bf16 = 32 MB
    size_t wbBytes = (size_t)O * I * sizeof(short);
    size_t xbBytes = (size_t)M * I * sizeof(short);  // 128 MB

    long long totalW = (long long)O * I;
    int dq_blocks = (int)((totalW / 8 + 255) / 256);
    dequant_kernel<<<dq_blocks, 256, 0, stream>>>(Wq, scales, zeros, mask,
                                                  scale2, Wb, O, I, G);

    dim3 grid(O / BN, M / BM);                       // (32, 128)
    if (ws_size >= wbBytes + xbBytes) {
        short* Xb = (short*)((char*)d_ws + wbBytes);
        int n8 = (int)(((size_t)M * I) / 8);
        int cv_blocks = (n8 + 255) / 256;
        convert_x_kernel<<<cv_blocks, 256, 0, stream>>>(x, Xb, n8);
        gemm_bb_kernel<<<grid, 256, 0, stream>>>(Xb, Wb, bias, out, M, O, I);
    } else {
        gemm_kernel<<<grid, 256, 0, stream>>>(x, Wb, bias, out, M, O, I);
    }
}

// Round 2
// 994.690 us; speedup vs baseline: 1.1677x; 1.1481x over previous
//
#include <hip/hip_runtime.h>
#include <hip/hip_bf16.h>
#include <stdint.h>

// ---------------------------------------------------------------------------
// SparseQuantLinear: out[m,o] = sum_i x[m,i] * W[o,i] + bias[o]
//   W[o,i] = mask[o,i] ? (W_q[o,i] - zeros[o,i/G]) * scales[o,i/G] * scale2[i] : 0
//
// R3: 256x256 8-phase-style GEMM (T2+T3+T4+T5):
//   - BK=32, 4-deep LDS ring buffer (4 x 32KB = 128KB), stage 3 tiles ahead
//   - counted vmcnt(8) at tile boundaries (never 0 in main loop)
//   - LDS XOR swizzle: 16B-unit ^= (row>>1)&3  (both-sides: pre-swizzled
//     global source for global_load_lds + swizzled ds_read address)
//   - s_setprio(1) around each 16-MFMA cluster
//   - bijective XCD-aware block swizzle
//   Pipeline: dequant W->bf16 (32MB ws) ; convert X->bf16 (128MB ws) ; gemm.
// ---------------------------------------------------------------------------

typedef short s16x8 __attribute__((ext_vector_type(8)));   // 8 bf16 bit-patterns
typedef short s16x4 __attribute__((ext_vector_type(4)));
typedef float f32x4 __attribute__((ext_vector_type(4)));

#define BM 256
#define BN 256
#define BK 32

static __device__ __forceinline__ short f2bf(float f) {
    __hip_bfloat16 h = __float2bfloat16(f);   // round-to-nearest-even
    return *reinterpret_cast<short*>(&h);
}

// ---------------- dequant: W_q(int32) -> W bf16 bits (short) ----------------
__global__ __launch_bounds__(256)
void dequant_kernel(const int* __restrict__ Wq,
                    const float* __restrict__ scales,
                    const float* __restrict__ zeros,
                    const void* __restrict__ mask_raw,
                    const float* __restrict__ scale2,
                    short* __restrict__ Wb,
                    int O, int I, int G) {
    // mask dtype probe (uniform across grid; ~1KB, L2-resident)
    __shared__ int lds_flag;
    if (threadIdx.x == 0) lds_flag = 0;
    __syncthreads();
    {
        unsigned v = ((const unsigned*)mask_raw)[threadIdx.x & 255];
        if (v > 1u) lds_flag = 1;          // benign same-value race
    }
    __syncthreads();
    const bool mask_is_byte = (lds_flag != 0);

    int idx = (blockIdx.x * 256 + threadIdx.x) * 8;   // O*I = 16.7M fits int
    if (idx >= O * I) return;
    int o = idx / I;
    int i = idx - o * I;              // multiple of 8; one group per 8 (G=128)
    int gi = o * (I / G) + i / G;
    float s = scales[gi];
    float z = zeros[gi];

    int4 w0 = *(const int4*)(Wq + idx);
    int4 w1 = *(const int4*)(Wq + idx + 4);
    float4 s2a = *(const float4*)(scale2 + i);
    float4 s2b = *(const float4*)(scale2 + i + 4);

    unsigned m[8];
    if (mask_is_byte) {
        unsigned long long mb = *(const unsigned long long*)((const unsigned char*)mask_raw + idx);
        #pragma unroll
        for (int j = 0; j < 8; ++j) m[j] = (unsigned)((mb >> (8 * j)) & 0xffULL);
    } else {
        int4 ma = *(const int4*)((const int*)mask_raw + idx);
        int4 mbv = *(const int4*)((const int*)mask_raw + idx + 4);
        m[0] = ma.x;  m[1] = ma.y;  m[2] = ma.z;  m[3] = ma.w;
        m[4] = mbv.x; m[5] = mbv.y; m[6] = mbv.z; m[7] = mbv.w;
    }

    float v[8];
    v[0] = ((float)w0.x - z) * s * s2a.x;
    v[1] = ((float)w0.y - z) * s * s2a.y;
    v[2] = ((float)w0.z - z) * s * s2a.z;
    v[3] = ((float)w0.w - z) * s * s2a.w;
    v[4] = ((float)w1.x - z) * s * s2b.x;
    v[5] = ((float)w1.y - z) * s * s2b.y;
    v[6] = ((float)w1.z - z) * s * s2b.z;
    v[7] = ((float)w1.w - z) * s * s2b.w;

    union { s16x8 v; int4 q; } out;
    #pragma unroll
    for (int j = 0; j < 8; ++j) {
        float masked = m[j] ? v[j] : 0.0f;
        out.v[j] = f2bf(masked);
    }
    *(int4*)(Wb + idx) = out.q;
}

// ---------------- convert: X fp32 -> bf16 (one pass) ------------------------
__global__ __launch_bounds__(256)
void convert_x_kernel(const float* __restrict__ X, short* __restrict__ Xb, int n8) {
    int c = blockIdx.x * 256 + threadIdx.x;
    if (c >= n8) return;
    size_t idx = (size_t)c * 8;
    float4 a = *(const float4*)(X + idx);
    float4 b = *(const float4*)(X + idx + 4);
    union { s16x8 v; int4 q; } o;
    o.v[0] = f2bf(a.x); o.v[1] = f2bf(a.y); o.v[2] = f2bf(a.z); o.v[3] = f2bf(a.w);
    o.v[4] = f2bf(b.x); o.v[5] = f2bf(b.y); o.v[6] = f2bf(b.z); o.v[7] = f2bf(b.w);
    *(int4*)(Xb + idx) = o.q;
}

// ---------------- 256x256 8-phase bf16 GEMM:  Out = Xb * Wb^T + bias --------
// LDS ring: 4 buffers x (A[256][32] + B[256][32]) bf16 = 4 x 32KB = 128KB.
// Tile t lives in buf t&3; tile t+3 staged during tile t (slot (t-1)&3, idle).
// Swizzle (involution on 16B units within a 64B row):
//   lds[row][u] holds logical element (row, u ^ ((row>>1)&3)).
// Read (row, lq) -> lds[row][lq ^ ((row>>1)&3)]; global source pre-swizzled.
__global__ __launch_bounds__(512, 2)
void gemm8_kernel(const short* __restrict__ Xb,
                  const short* __restrict__ Wb,
                  const float* __restrict__ bias,
                  float* __restrict__ Out,
                  int M, int N, int K) {
    __shared__ short lds[4 * 16384];   // 128 KiB

    const int tid  = threadIdx.x;
    const int wave = tid >> 6;
    const int lane = tid & 63;
    const int lr   = lane & 15;          // row-within-16 (A) / col (B)
    const int lq   = lane >> 4;          // k unit: lq*8 shorts
    const int sw   = (lr >> 1) & 3;      // swizzle term: (row>>1)&3 == (lr>>1)&3
    const int wm   = (wave >> 2) * 128;  // 2 M-waves
    const int wn   = (wave & 3) * 64;    // 4 N-waves

    // bijective XCD-aware swizzle of the flat block id
    const int gx  = gridDim.x;
    const int nwg = gx * gridDim.y;
    int bid = blockIdx.y * gx + blockIdx.x;
    if ((nwg & 7) == 0) {
        int cpx = nwg >> 3;
        bid = (bid & 7) * cpx + (bid >> 3);
    }
    const int bx = bid % gx;
    const int by = bid / gx;
    const int m0 = by * BM;
    const int n0 = bx * BN;

    const int NT = K / BK;               // 128

    // staging source coords (pre-swizzled column unit)
    const int srow = tid >> 2;                          // 0..127
    const int scol = (((tid & 3) ^ ((tid >> 3) & 3))) * 8;
    const short* gA = Xb + (size_t)(m0 + srow) * K + scol;
    const short* gB = Wb + (size_t)(n0 + srow) * K + scol;

    // per-lane LDS read offsets (shorts), within a buffer
    const int laneA = (wm + lr) * 32 + ((lq ^ sw) << 3);
    const int laneB = 8192 + (wn + lr) * 32 + ((lq ^ sw) << 3);
    // wave-uniform LDS staging bases (shorts), within a buffer
    const int dstA = wave * 512;
    const int dstB = 8192 + wave * 512;

    f32x4 acc[8][4] = {};

    #define STAGE_A(t_) do {                                                    \
        int b_  = ((t_) & 3) * 16384;                                           \
        int k_  = (t_) * BK;                                                    \
        __builtin_amdgcn_global_load_lds(                                       \
            (const __attribute__((address_space(1))) void*)(gA + (size_t)k_),   \
            (__attribute__((address_space(3))) void*)(lds + b_ + dstA), 16, 0, 0); \
        __builtin_amdgcn_global_load_lds(                                       \
            (const __attribute__((address_space(1))) void*)(gA + (size_t)128 * K + k_), \
            (__attribute__((address_space(3))) void*)(lds + b_ + dstA + 4096), 16, 0, 0); \
    } while (0)
    #define STAGE_B(t_) do {                                                    \
        int b_  = ((t_) & 3) * 16384;                                           \
        int k_  = (t_) * BK;                                                    \
        __builtin_amdgcn_global_load_lds(                                       \
            (const __attribute__((address_space(1))) void*)(gB + (size_t)k_),   \
            (__attribute__((address_space(3))) void*)(lds + b_ + dstB), 16, 0, 0); \
        __builtin_amdgcn_global_load_lds(                                       \
            (const __attribute__((address_space(1))) void*)(gB + (size_t)128 * K + k_), \
            (__attribute__((address_space(3))) void*)(lds + b_ + dstB + 4096), 16, 0, 0); \
    } while (0)

    // prologue: stage tiles 0..2 (12 loads); tile 0 complete when vmcnt<=8
    STAGE_A(0); STAGE_B(0);
    STAGE_A(1); STAGE_B(1);
    STAGE_A(2); STAGE_B(2);
    asm volatile("s_waitcnt vmcnt(8)" ::: "memory");
    __builtin_amdgcn_s_barrier();

    for (int t = 0; t < NT; ++t) {
        const short* base = lds + ((t & 3) << 14);
        s16x8 bfr[4], af[4];

        // ---- phase A: mi 0..3  (reads 4 B-frags + 4 A-frags; stages A of t+3)
        #pragma unroll
        for (int ni = 0; ni < 4; ++ni)
            bfr[ni] = *(const s16x8*)(base + laneB + ni * 512);
        #pragma unroll
        for (int mi = 0; mi < 4; ++mi)
            af[mi] = *(const s16x8*)(base + laneA + mi * 512);
        if (t < NT - 3) STAGE_A(t + 3);
        __builtin_amdgcn_s_barrier();
        __builtin_amdgcn_s_setprio(1);
        #pragma unroll
        for (int mi = 0; mi < 4; ++mi)
            #pragma unroll
            for (int ni = 0; ni < 4; ++ni)
                acc[mi][ni] = __builtin_amdgcn_mfma_f32_16x16x32_bf16(
                    af[mi], bfr[ni], acc[mi][ni], 0, 0, 0);
        __builtin_amdgcn_s_setprio(0);
        __builtin_amdgcn_s_barrier();

        // ---- phase B: mi 4..7  (reads 4 A-frags; B held in regs; stages B of t+3)
        #pragma unroll
        for (int mi = 0; mi < 4; ++mi)
            af[mi] = *(const s16x8*)(base + laneA + (mi + 4) * 512);
        if (t < NT - 3) STAGE_B(t + 3);
        __builtin_amdgcn_s_barrier();
        __builtin_amdgcn_s_setprio(1);
        #pragma unroll
        for (int mi = 0; mi < 4; ++mi)
            #pragma unroll
            for (int ni = 0; ni < 4; ++ni)
                acc[mi + 4][ni] = __builtin_amdgcn_mfma_f32_16x16x32_bf16(
                    af[mi], bfr[ni], acc[mi + 4][ni], 0, 0, 0);
        __builtin_amdgcn_s_setprio(0);
        // boundary: tile t+1 must be resident; tiles t+2,t+3 (8 loads) in flight
        if (t < NT - 3)       asm volatile("s_waitcnt vmcnt(8)" ::: "memory");
        else if (t == NT - 3) asm volatile("s_waitcnt vmcnt(4)" ::: "memory");
        else                  asm volatile("s_waitcnt vmcnt(0)" ::: "memory");
        __builtin_amdgcn_s_barrier();
    }
    #undef STAGE_A
    #undef STAGE_B

    // epilogue: C/D layout col = lane&15, row = lq*4 + r   (m89/m91 verified)
    #pragma unroll
    for (int ni = 0; ni < 4; ++ni) {
        int nc = n0 + wn + ni * 16 + lr;
        float bv = bias[nc];
        #pragma unroll
        for (int mi = 0; mi < 8; ++mi) {
            int mr = m0 + wm + mi * 16 + lq * 4;
            #pragma unroll
            for (int r = 0; r < 4; ++r)
                Out[(size_t)(mr + r) * N + nc] = acc[mi][ni][r] + bv;
        }
    }
}

// ---------------- fallback GEMM (verified, fp32 A staged in regs) -----------
#define FBM 128
#define FBN 128
#define FBK 64
#define LDSS 72

__global__ __launch_bounds__(256, 2)
void gemm_kernel(const float* __restrict__ X,
                 const short* __restrict__ Wb,
                 const float* __restrict__ bias,
                 float* __restrict__ Out,
                 int M, int N, int K) {
    __shared__ short As[FBM * LDSS];
    __shared__ short Bs[FBN * LDSS];

    const int tid  = threadIdx.x;
    const int m0   = blockIdx.y * FBM;
    const int n0   = blockIdx.x * FBN;
    const int wave = tid >> 6;
    const int lane = tid & 63;
    const int wm   = (wave >> 1) * 64;
    const int wn   = (wave & 1) * 64;
    const int lr   = lane & 15;
    const int lq   = lane >> 4;

    f32x4 acc[4][4] = {};

    for (int k0 = 0; k0 < K; k0 += FBK) {
        #pragma unroll
        for (int t = 0; t < 8; ++t) {
            int c   = tid + t * 256;
            int row = c >> 4;
            int col = (c & 15) * 4;
            float4 xv = *(const float4*)(X + (size_t)(m0 + row) * K + k0 + col);
            s16x4 bv;
            bv[0] = f2bf(xv.x); bv[1] = f2bf(xv.y);
            bv[2] = f2bf(xv.z); bv[3] = f2bf(xv.w);
            *(s16x4*)&As[row * LDSS + col] = bv;
        }
        #pragma unroll
        for (int t = 0; t < 4; ++t) {
            int c   = tid + t * 256;
            int row = c >> 3;
            int col = (c & 7) * 8;
            s16x8 wv = *(const s16x8*)(Wb + (size_t)(n0 + row) * K + k0 + col);
            *(s16x8*)&Bs[row * LDSS + col] = wv;
        }
        __syncthreads();

        #pragma unroll
        for (int kk = 0; kk < FBK; kk += 32) {
            s16x8 af[4], bf[4];
            #pragma unroll
            for (int mi = 0; mi < 4; ++mi)
                af[mi] = *(const s16x8*)&As[(wm + mi * 16 + lr) * LDSS + kk + lq * 8];
            #pragma unroll
            for (int ni = 0; ni < 4; ++ni)
                bf[ni] = *(const s16x8*)&Bs[(wn + ni * 16 + lr) * LDSS + kk + lq * 8];
            #pragma unroll
            for (int mi = 0; mi < 4; ++mi)
                #pragma unroll
                for (int ni = 0; ni < 4; ++ni)
                    acc[mi][ni] = __builtin_amdgcn_mfma_f32_16x16x32_bf16(
                        af[mi], bf[ni], acc[mi][ni], 0, 0, 0);
        }
        __syncthreads();
    }

    #pragma unroll
    for (int ni = 0; ni < 4; ++ni) {
        int nc = n0 + wn + ni * 16 + lr;
        float bv = bias[nc];
        #pragma unroll
        for (int mi = 0; mi < 4; ++mi) {
            int mr = m0 + wm + mi * 16 + lq * 4;
            #pragma unroll
            for (int r = 0; r < 4; ++r)
                Out[(size_t)(mr + r) * N + nc] = acc[mi][ni][r] + bv;
        }
    }
}

// ---------------------------------------------------------------------------
extern "C" void kernel_launch(void* const* d_in, const int* in_sizes, int n_in,
                              void* d_out, int out_size, void* d_ws, size_t ws_size,
                              hipStream_t stream) {
    const float* x      = (const float*)d_in[0];
    const int*   Wq     = (const int*)d_in[1];
    const float* scales = (const float*)d_in[2];
    const float* zeros  = (const float*)d_in[3];
    const void*  mask   = (const void*)d_in[4];   // bool: byte OR int32 (auto-detect)
    const float* scale2 = (const float*)d_in[5];
    const float* bias   = (const float*)d_in[6];
    float*       out    = (float*)d_out;

    const int I = in_sizes[5];                       // 4096
    const int O = in_sizes[6];                       // 4096
    const int M = (int)(in_sizes[0] / I);            // 16384
    const int G = (int)(((long long)O * I) / in_sizes[2]);  // 128

    short* Wb = (short*)d_ws;                        // O*I bf16 = 32 MB
    size_t wbBytes = (size_t)O * I * sizeof(short);
    size_t xbBytes = (size_t)M * I * sizeof(short);  // 128 MB

    long long totalW = (long long)O * I;
    int dq_blocks = (int)((totalW / 8 + 255) / 256);
    dequant_kernel<<<dq_blocks, 256, 0, stream>>>(Wq, scales, zeros, mask,
                                                  scale2, Wb, O, I, G);

    const bool shape_ok = (M % BM == 0) && (O % BN == 0) && (I % BK == 0)
                          && (I / BK >= 4);
    if (shape_ok && ws_size >= wbBytes + xbBytes) {
        short* Xb = (short*)((char*)d_ws + wbBytes);
        int n8 = (int)(((size_t)M * I) / 8);
        int cv_blocks = (n8 + 255) / 256;
        convert_x_kernel<<<cv_blocks, 256, 0, stream>>>(x, Xb, n8);
        dim3 grid(O / BN, M / BM);                   // (16, 64)
        gemm8_kernel<<<grid, 512, 0, stream>>>(Xb, Wb, bias, out, M, O, I);
    } else {
        dim3 grid(O / FBN, M / FBM);                 // (32, 128)
        gemm_kernel<<<grid, 256, 0, stream>>>(x, Wb, bias, out, M, O, I);
    }
}